// Round 29
// baseline (216.563 us; speedup 1.0000x reference)
//
#include <hip/hip_runtime.h>
#include <math.h>

typedef unsigned int u32;
typedef unsigned long long u64;
typedef _Float16 f16x8 __attribute__((ext_vector_type(8)));
typedef _Float16 f16x4 __attribute__((ext_vector_type(4)));
typedef float f32x4 __attribute__((ext_vector_type(4)));
typedef __attribute__((address_space(1))) const char gch;
typedef __attribute__((address_space(3))) char lch;

#define ZD 256      // z_dim (C)
#define KC 1024     // number of codes
#define TT 4096     // T
#define BB 16       // B
#define NROWS (BB*TT)     // 65536
#define TAU 0.12f         // margin threshold (~6 sigma of fp16 pairwise err)
#define FLAGCAP 32768

__device__ __forceinline__ u32 flip32(float s) {
    int i = __float_as_int(s);
    return (u32)(i ^ ((i >> 31) | 0x80000000));
}
__device__ __forceinline__ float unflip32(u32 u) {
    int m = (~(((int)u) >> 31)) | 0x80000000;
    return __int_as_float((int)(u ^ (u32)m));
}

// ---------------- prep: zero cnt, re=||e||^2, emb->fp16 ----------------
__global__ __launch_bounds__(256)
void vq_prep_kernel(const float* __restrict__ emb, _Float16* __restrict__ eh,
                    float* __restrict__ re, int* __restrict__ cnt) {
    int gid = blockIdx.x * 256 + threadIdx.x;
    if (gid < 2) cnt[gid] = 0;      // cnt[0]=flag count

    int code = gid >> 6;   // one wave per code
    int lane = threadIdx.x & 63;
    float4 v = *(const float4*)(emb + (size_t)code * ZD + lane * 4);
    float s = v.x*v.x + v.y*v.y + v.z*v.z + v.w*v.w;
    #pragma unroll
    for (int off = 32; off; off >>= 1) s += __shfl_down(s, off, 64);
    if (lane == 0) re[code] = s;

    f16x4 hv;
    hv[0] = (_Float16)v.x; hv[1] = (_Float16)v.y;
    hv[2] = (_Float16)v.z; hv[3] = (_Float16)v.w;
    *(f16x4*)(eh + (size_t)code * ZD + lane * 4) = hv;
}

// ---- stage one 16-code tile (8KB) for one code-half; 4 waves x 2 loads ----
__device__ __forceinline__ void stage_tile16(const char* ehc_h, char* dstbase,
                                             int h, int wr, int l) {
    const int srow = h * 8192;              // 16 codes * 512B
    #pragma unroll
    for (int j = 0; j < 2; ++j) {
        const int gi  = wr * 2 + j;         // 0..7
        const int c   = 2 * gi + (l >> 5);  // local code this lane's 16B lands in
        const int kbs = (l & 31) * 16;
        const int off = srow + c * 512 + (kbs ^ ((c & 7) << 4));
        __builtin_amdgcn_global_load_lds((gch*)(ehc_h + off),
                                         (lch*)(dstbase + gi * 1024), 16, 0, 0);
    }
}

// ---- one 16-code phase: 8 ds_read_b128 + 32 MFMA (2 rowgroups) ----
__device__ __forceinline__ void compute16(const char* tb, int codeg0,
                                          const f16x8 (&ah)[2][8], const float* reL,
                                          float (&v1)[8], float (&v2)[8], int (&i1)[8],
                                          int lane15, int lk) {
    const int sw = (lane15 & 7) << 4;
    f16x8 bh[8];
    #pragma unroll
    for (int ks = 0; ks < 8; ++ks)
        bh[ks] = *(const f16x8*)(tb + lane15 * 512 + ((lk * 16 + ks * 64) ^ sw));

    f32x4 a0 = {0.f, 0.f, 0.f, 0.f};
    f32x4 a1 = {0.f, 0.f, 0.f, 0.f};
    __builtin_amdgcn_s_setprio(1);
    #pragma unroll
    for (int ks = 0; ks < 8; ++ks) {
        a0 = __builtin_amdgcn_mfma_f32_16x16x32_f16(ah[0][ks], bh[ks], a0, 0, 0, 0);
        a1 = __builtin_amdgcn_mfma_f32_16x16x32_f16(ah[1][ks], bh[ks], a1, 0, 0, 0);
    }
    __builtin_amdgcn_s_setprio(0);

    const int codeg = codeg0 + lane15;
    const float rc = reL[codeg];
    #pragma unroll
    for (int r = 0; r < 4; ++r) {
        float s0 = fmaf(-2.f, a0[r], rc);
        float n2a = fminf(fmaxf(v1[r], s0), v2[r]);          // med3
        i1[r] = (s0 < v1[r]) ? codeg : i1[r];
        v1[r] = fminf(v1[r], s0);
        v2[r] = n2a;
        float s1 = fmaf(-2.f, a1[r], rc);
        float n2b = fminf(fmaxf(v1[4 + r], s1), v2[4 + r]);
        i1[4 + r] = (s1 < v1[4 + r]) ? codeg : i1[4 + r];
        v1[4 + r] = fminf(v1[4 + r], s1);
        v2[4 + r] = n2b;
    }
}

// ---------------- fused argmin: code-split halves within block ----------------
// 512 blocks x 512 threads. Block: 128 rows. Waves 0-3: codes [0,512); waves 4-7:
// codes [512,1024); each wave 32 rows (2 rowgroups). Two ring-3 x 8KB tile rings,
// counted vmcnt(2). Epilogue merges halves' top-2 per row in LDS. LDS traffic/CU
// halves vs r22 (each wave reads only half the codebook).
__global__ __launch_bounds__(512, 4)
void vq_argmin_mfma(const float* __restrict__ z, const _Float16* __restrict__ eh,
                    const float* __restrict__ emb, const float* __restrict__ re,
                    float* __restrict__ out, float* __restrict__ lossP,
                    int* __restrict__ idx, int* __restrict__ cnt,
                    int* __restrict__ flags) {
    __shared__ __align__(16) char lds[53760];
    // ringA 0..24576 | ringB 24576..49152 | reL 49152..53248 | zsqL 53248..53760
    float* reL  = (float*)(lds + 49152);    // 1024 f32
    float* zsqL = (float*)(lds + 53248);    // 128 f32
    // epilogue aliases (ring area, dead by then):
    int*   idsL   = (int*)lds;              // 128 i32            [0, 512)
    float* wlossL = (float*)(lds + 512);    // 2 f32              [512, 544)
    float* v1h    = (float*)(lds + 1024);   // [2][128]           [1024, 2048)
    float* v2h    = (float*)(lds + 2048);   // [2][128]           [2048, 3072)
    int*   i1h    = (int*)(lds + 3072);     // [2][128]           [3072, 4096)

    const int tid = threadIdx.x;
    const int w   = tid >> 6;       // 0..7
    const int l   = tid & 63;
    const int lane15 = l & 15;
    const int lk     = l >> 4;
    const int hf  = w >> 2;         // code half 0/1
    const int wr  = w & 3;          // row-wave within half
    const int r0  = blockIdx.x * 128;
    const int b   = r0 >> 12;
    const int t0  = r0 & 4095;
    const char* ehc_h = (const char*)eh + (size_t)hf * 512 * 512;  // half's codes

    *(float2*)(reL + tid * 2) = *(const float2*)(re + tid * 2);

    // ---- z prologue: block-wide staging, 4 rounds of 64 c-cols x 128 t (32KB) ----
    // round layout: [cl 0..63][t 0..127] f32; chunk = w*4+j covers 2 c-cols.
    f16x8 ah[2][8];
    float zsq[2] = {0.f, 0.f};
    {
        const char* zb = (const char*)(z + (size_t)b * ZD * TT + t0);
        #pragma unroll
        for (int round = 0; round < 4; ++round) {
            #pragma unroll
            for (int j = 0; j < 4; ++j) {
                const int chunk = w * 4 + j;            // 0..31
                const int c  = round * 64 + chunk * 2 + (l >> 5);
                const char* src = zb + ((size_t)c * TT + (l & 31) * 4) * 4;
                __builtin_amdgcn_global_load_lds((gch*)src,
                                                 (lch*)(lds + chunk * 1024), 16, 0, 0);
            }
            asm volatile("s_waitcnt vmcnt(0)" ::: "memory");
            __builtin_amdgcn_sched_barrier(0);
            __syncthreads();        // cross-wave reads of staged z
            #pragma unroll
            for (int rg = 0; rg < 2; ++rg) {
                const int t_loc = wr * 32 + rg * 16 + lane15;
                #pragma unroll
                for (int ks2 = 0; ks2 < 2; ++ks2) {
                    const int cl0 = ks2 * 32 + lk * 8;
                    f16x8 h;
                    #pragma unroll
                    for (int j = 0; j < 8; ++j) {
                        float v = *(const float*)(lds + (cl0 + j) * 512 + t_loc * 4);
                        zsq[rg] = fmaf(v, v, zsq[rg]);
                        h[j] = (_Float16)v;
                    }
                    ah[rg][round * 2 + ks2] = h;
                }
            }
            __syncthreads();        // reads done before next round overwrites
        }
    }
    #pragma unroll
    for (int rg = 0; rg < 2; ++rg) {
        zsq[rg] += __shfl_xor(zsq[rg], 16, 64);
        zsq[rg] += __shfl_xor(zsq[rg], 32, 64);
    }
    // every lane holds full zsq for row wr*32 + rg*16 + lane15; half A writes it
    if (hf == 0 && l < 16) {
        zsqL[wr * 32 + l]      = zsq[0];
        zsqL[wr * 32 + 16 + l] = zsq[1];
    }

    float v1[8], v2[8];
    int   i1[8];
    #pragma unroll
    for (int s8 = 0; s8 < 8; ++s8) { v1[s8] = 3.4e38f; v2[s8] = 3.4e38f; i1[s8] = 0; }

    // drain ds ops; begin e-staging (depth 2) into this half's ring
    asm volatile("s_waitcnt vmcnt(0) lgkmcnt(0)" ::: "memory");
    __syncthreads();
    char* ring = lds + hf * 24576;
    stage_tile16(ehc_h, ring,        0, wr, l);
    stage_tile16(ehc_h, ring + 8192, 1, wr, l);

    // Ring-3 per half: phase h reads buf[h%3]; stage(h+2) (after barrier h) writes
    // buf[(h-1)%3], read-complete before barrier h. Per-wave 2 glds/stage ->
    // at phase-h wait only stage h+1 outstanding -> vmcnt(2).
    const int cbase = hf * 512;
    for (int h = 0; h < 31; ++h) {
        asm volatile("s_waitcnt vmcnt(2)" ::: "memory");
        __builtin_amdgcn_sched_barrier(0);
        __builtin_amdgcn_s_barrier();
        if (h < 30) stage_tile16(ehc_h, ring + ((h + 2) % 3) * 8192, h + 2, wr, l);
        compute16(ring + (h % 3) * 8192, cbase + h * 16, ah, reL, v1, v2, i1, lane15, lk);
    }
    asm volatile("s_waitcnt vmcnt(0)" ::: "memory");
    __builtin_amdgcn_sched_barrier(0);
    __builtin_amdgcn_s_barrier();
    compute16(ring + (31 % 3) * 8192, cbase + 31 * 16, ah, reL, v1, v2, i1, lane15, lk);

    // reduce across the 16 lanes holding different codes (same rows)
    #pragma unroll
    for (int off = 1; off < 16; off <<= 1) {
        #pragma unroll
        for (int s8 = 0; s8 < 8; ++s8) {
            float ov1 = __shfl_xor(v1[s8], off, 64);
            int   oi1 = __shfl_xor(i1[s8], off, 64);
            float ov2 = __shfl_xor(v2[s8], off, 64);
            float nv2 = fminf(fmaxf(v1[s8], ov1), fminf(v2[s8], ov2));
            if (ov1 < v1[s8] || (ov1 == v1[s8] && oi1 < i1[s8])) { v1[s8] = ov1; i1[s8] = oi1; }
            v2[s8] = nv2;
        }
    }

    __syncthreads();    // all compute done -> ring dead, aliases safe
    if (lane15 == 0) {
        #pragma unroll
        for (int s8 = 0; s8 < 8; ++s8) {
            const int rg = s8 >> 2, rr = s8 & 3;
            const int row = wr * 32 + rg * 16 + lk * 4 + rr;    // local row 0..127
            v1h[hf * 128 + row] = v1[s8];
            v2h[hf * 128 + row] = v2[s8];
            i1h[hf * 128 + row] = i1[s8];
        }
    }
    __syncthreads();

    // merge halves (threads 0..127 = one row each); emit idx/loss/flags
    if (tid < 128) {
        const float va1 = v1h[tid], vb1 = v1h[128 + tid];
        const float va2 = v2h[tid], vb2 = v2h[128 + tid];
        const int   ia1 = i1h[tid], ib1 = i1h[128 + tid];
        float nv1; int ni1;
        if (vb1 < va1) { nv1 = vb1; ni1 = ib1; }    // tie -> half A (lower code)
        else           { nv1 = va1; ni1 = ia1; }
        const float nv2 = fminf(fmaxf(va1, vb1), fminf(va2, vb2));
        idsL[tid] = ni1;
        idx[r0 + tid] = ni1;
        const bool fl = (nv2 - nv1 < TAU);
        float lv = fl ? zsqL[tid] : (zsqL[tid] + nv1);
        if (fl) {
            int p = atomicAdd(cnt, 1);
            if (p < FLAGCAP) flags[p] = (r0 + tid) | (ni1 << 16);
        }
        #pragma unroll
        for (int off = 32; off; off >>= 1) lv += __shfl_down(lv, off, 64);
        if (l == 0) wlossL[tid >> 6] = lv;
    }
    __syncthreads();
    if (tid == 0) lossP[blockIdx.x] = wlossL[0] + wlossL[1];

    // out-write: wave w covers c in [32w, 32w+32), all 128 rows
    {
        const int c0 = w * 32;
        float* ob = out + (size_t)b * ZD * TT + t0;
        #pragma unroll
        for (int half = 0; half < 2; ++half) {
            const int tt = half * 64 + l;
            const int ii = idsL[tt];
            const float4* er4 = (const float4*)(emb + (size_t)ii * ZD + c0);
            #pragma unroll
            for (int c4 = 0; c4 < 8; ++c4) {
                float4 ev = er4[c4];
                float* o0 = ob + (size_t)(c0 + c4 * 4) * TT + tt;
                o0[0]      = ev.x;
                o0[TT]     = ev.y;
                o0[2 * TT] = ev.z;
                o0[3 * TT] = ev.w;
            }
        }
    }
}

// ------- fixup (blocks 0..255) + sparsity (blocks 256..383); 1024 threads each -------
__global__ __launch_bounds__(1024)
void vq_fixspar(const float* __restrict__ z, const float* __restrict__ emb,
                const float* __restrict__ re, const int* __restrict__ cnt,
                const int* __restrict__ flags, float* __restrict__ out,
                int* __restrict__ idx, float* __restrict__ sparLse,
                float* __restrict__ addP) {
    const int tid = threadIdx.x;
    const int w   = tid >> 6;       // 0..15
    const int lane = tid & 63;

    if (blockIdx.x >= 256) {
        // ---- sparsity: 8 rows, one code per thread, complete lse per row ----
        __shared__ __align__(16) float er[8][260];
        __shared__ float wmaxS[8][16];
        __shared__ float wsumS[8][16];
        const int sb = blockIdx.x - 256;        // 0..127
        const int r0 = sb * 8;

        for (int i = tid; i < 8 * 256; i += 1024) er[i >> 8][i & 255] = emb[(size_t)r0 * ZD + i];
        __syncthreads();

        const int c = tid;                      // this thread's code
        const float4* ec = (const float4*)(emb + (size_t)c * ZD);
        float a[8] = {0.f,0.f,0.f,0.f,0.f,0.f,0.f,0.f};
        #pragma unroll 4
        for (int k4 = 0; k4 < ZD / 4; ++k4) {
            float4 e4 = ec[k4];
            #pragma unroll
            for (int r = 0; r < 8; ++r) {
                const float* a4 = &er[r][k4 * 4];
                a[r] = fmaf(e4.x, a4[0], fmaf(e4.y, a4[1],
                       fmaf(e4.z, a4[2], fmaf(e4.w, a4[3], a[r]))));
            }
        }
        #pragma unroll
        for (int r = 0; r < 8; ++r) {
            float m = a[r];
            #pragma unroll
            for (int off = 32; off; off >>= 1) m = fmaxf(m, __shfl_xor(m, off, 64));
            if (lane == 0) wmaxS[r][w] = m;
        }
        __syncthreads();
        float M[8];
        #pragma unroll
        for (int r = 0; r < 8; ++r) {
            float m = wmaxS[r][0];
            #pragma unroll
            for (int j = 1; j < 16; ++j) m = fmaxf(m, wmaxS[r][j]);
            M[r] = m;
            float se = expf(a[r] - m);
            #pragma unroll
            for (int off = 32; off; off >>= 1) se += __shfl_xor(se, off, 64);
            if (lane == 0) wsumS[r][w] = se;
        }
        __syncthreads();
        if (tid < 8) {
            float S = 0.f;
            #pragma unroll
            for (int j = 0; j < 16; ++j) S += wsumS[tid][j];
            sparLse[r0 + tid] = M[tid] + logf(S);
        }
        return;
    }

    // ---- fixup: each thread ONE code, 8 flagged rows per pass ----
    __shared__ __align__(16) float zs[8][ZD];
    __shared__ u64 sb2[16][8];
    __shared__ int nwS[8];
    __shared__ float addS;
    int n = cnt[0];
    if (n > FLAGCAP) n = FLAGCAP;
    float blkLoss = 0.f;    // meaningful at tid==0 only

    const int c = tid;              // this thread's code (1024 codes exactly)
    const float4* ec = (const float4*)(emb + (size_t)c * ZD);
    const float rc = re[c];

    for (int base = blockIdx.x * 8; base < n; base += 256 * 8) {
        const int nr = (n - base < 8) ? (n - base) : 8;
        __syncthreads();
        for (int i = tid; i < nr * 256; i += 1024) {
            const int r = i >> 8, k = i & 255;
            const int rowg = flags[base + r] & 0xFFFF;
            zs[r][k] = z[(size_t)(rowg >> 12) * ZD * TT + (size_t)k * TT + (rowg & 4095)];
        }
        __syncthreads();

        float a[8] = {0.f,0.f,0.f,0.f,0.f,0.f,0.f,0.f};
        #pragma unroll 4
        for (int k4 = 0; k4 < ZD / 4; ++k4) {
            float4 e4 = ec[k4];
            #pragma unroll
            for (int r = 0; r < 8; ++r) {
                const float* a4 = &zs[r][k4 * 4];
                a[r] = fmaf(e4.x, a4[0], fmaf(e4.y, a4[1],
                       fmaf(e4.z, a4[2], fmaf(e4.w, a4[3], a[r]))));
            }
        }
        #pragma unroll
        for (int r = 0; r < 8; ++r) {
            if (r < nr) {
                float s = fmaf(-2.f, a[r], rc);
                u64 bv = ((u64)flip32(s) << 32) | (u32)c;
                #pragma unroll
                for (int off = 32; off; off >>= 1) {
                    u64 o = (u64)__shfl_xor((long long)bv, off, 64);
                    if (o < bv) bv = o;
                }
                if (lane == 0) sb2[w][r] = bv;
            }
        }
        __syncthreads();
        if (tid == 0) addS = 0.f;
        __syncthreads();
        if (tid < nr) {
            u64 m = sb2[0][tid];
            #pragma unroll
            for (int j = 1; j < 16; ++j) if (sb2[j][tid] < m) m = sb2[j][tid];
            const int nc  = (int)(u32)(m & 0xFFFFFFFFull);
            const float s = unflip32((u32)(m >> 32));
            const int rowg = flags[base + tid] & 0xFFFF;
            const int old  = (flags[base + tid] >> 16) & 1023;
            atomicAdd(&addS, s);
            if (nc != old) { idx[rowg] = nc; nwS[tid] = nc; }
            else nwS[tid] = -1;
        }
        __syncthreads();
        if (tid == 0) blkLoss += addS;
        for (int r = 0; r < nr; ++r) {
            const int nw = nwS[r];
            if (nw >= 0 && tid < 256) {
                const int rowg = flags[base + r] & 0xFFFF;
                out[(size_t)(rowg >> 12) * ZD * TT + (size_t)tid * TT + (rowg & 4095)]
                    = emb[(size_t)nw * ZD + tid];
            }
        }
    }
    if (tid == 0) addP[blockIdx.x] = blkLoss;
}

// ------- final: histogram->perplexity; loss sums; sparsity sum (lse - re) -------
__global__ __launch_bounds__(1024)
void vq_final_kernel(const int* __restrict__ idx, const float* __restrict__ re,
                     const float* __restrict__ sparLse, const float* __restrict__ lossP,
                     const float* __restrict__ addP, float* __restrict__ scal) {
    __shared__ int   histL[4][1024];
    __shared__ float red[1024];
    const int tid = threadIdx.x;
    const int g   = tid >> 8;       // 4 sub-histograms (4 waves each)

    histL[0][tid] = 0; histL[1][tid] = 0; histL[2][tid] = 0; histL[3][tid] = 0;
    __syncthreads();
    #pragma unroll 4
    for (int i = 0; i < 64; ++i)
        atomicAdd(&histL[g][idx[i * 1024 + tid]], 1);
    __syncthreads();
    const int hc = histL[0][tid] + histL[1][tid] + histL[2][tid] + histL[3][tid];
    float p = (float)hc * (1.0f / (float)NROWS);
    red[tid] = -p * logf(p + 1e-10f);
    __syncthreads();
    for (int st = 512; st; st >>= 1) {
        if (tid < st) red[tid] += red[tid + st];
        __syncthreads();
    }
    if (tid == 0) scal[2] = expf(red[0]);
    __syncthreads();

    // loss: 512 argmin partials + 256 fixup partials
    red[tid] = (tid < 512 ? lossP[tid] : 0.f) + ((tid < 256) ? addP[tid] : 0.f);
    __syncthreads();
    for (int st = 512; st; st >>= 1) {
        if (tid < st) red[tid] += red[tid + st];
        __syncthreads();
    }
    if (tid == 0) { scal[0] = red[0]; scal[1] = red[0]; }
    __syncthreads();

    // sparsity: sum over rows of (lse - exact diag re)
    red[tid] = sparLse[tid] - re[tid];
    __syncthreads();
    for (int st = 512; st; st >>= 1) {
        if (tid < st) red[tid] += red[tid + st];
        __syncthreads();
    }
    if (tid == 0) scal[3] = red[0] * (1.0f / (float)KC);
}

extern "C" void kernel_launch(void* const* d_in, const int* in_sizes, int n_in,
                              void* d_out, int out_size, void* d_ws, size_t ws_size,
                              hipStream_t stream) {
    const float* z   = (const float*)d_in[0];
    const float* emb = (const float*)d_in[1];
    float* out = (float*)d_out;
    const size_t NOUT = (size_t)BB * ZD * TT;    // 16777216
    float* scal = out + NOUT;                    // [qut, enc, perp, sparsity]

    float* re      = (float*)d_ws;               // 1024 f32
    int*   cnt     = (int*)(re + KC);            // 4 i32
    int*   flags   = cnt + 4;                    // FLAGCAP i32
    float* sparLse = (float*)(flags + FLAGCAP);  // 1024 f32
    float* lossP   = sparLse + KC;               // 512 f32
    float* addP    = lossP + 512;                // 256 f32
    int*   idx     = (int*)(addP + 256);         // 65536 i32
    _Float16* eh   = (_Float16*)(idx + NROWS);   // 1024*256 f16

    vq_prep_kernel<<<256, 256, 0, stream>>>(emb, eh, re, cnt);
    vq_argmin_mfma<<<NROWS / 128, 512, 0, stream>>>(z, eh, emb, re, out, lossP, idx,
                                                    cnt, flags);
    vq_fixspar<<<384, 1024, 0, stream>>>(z, emb, re, cnt, flags, out, idx,
                                         sparLse, addP);
    vq_final_kernel<<<1, 1024, 0, stream>>>(idx, re, sparLse, lossP, addP, scal);
}

// Round 30
// 142.797 us; speedup vs baseline: 1.5166x; 1.5166x over previous
//
#include <hip/hip_runtime.h>
#include <math.h>

typedef unsigned int u32;
typedef unsigned long long u64;
typedef _Float16 f16x8 __attribute__((ext_vector_type(8)));
typedef _Float16 f16x4 __attribute__((ext_vector_type(4)));
typedef float f32x4 __attribute__((ext_vector_type(4)));
typedef __attribute__((address_space(1))) const char gch;
typedef __attribute__((address_space(3))) char lch;

#define ZD 256      // z_dim (C)
#define KC 1024     // number of codes
#define TT 4096     // T
#define BB 16       // B
#define NROWS (BB*TT)     // 65536
#define TAU 0.12f         // margin threshold (~6 sigma of fp16 pairwise err)
#define FLAGCAP 32768

__device__ __forceinline__ u32 flip32(float s) {
    int i = __float_as_int(s);
    return (u32)(i ^ ((i >> 31) | 0x80000000));
}
__device__ __forceinline__ float unflip32(u32 u) {
    int m = (~(((int)u) >> 31)) | 0x80000000;
    return __int_as_float((int)(u ^ (u32)m));
}

// ---------------- prep: zero cnt, re=||e||^2, emb->fp16 ----------------
__global__ __launch_bounds__(256)
void vq_prep_kernel(const float* __restrict__ emb, _Float16* __restrict__ eh,
                    float* __restrict__ re, int* __restrict__ cnt) {
    int gid = blockIdx.x * 256 + threadIdx.x;
    if (gid < 2) cnt[gid] = 0;      // cnt[0]=flag count

    int code = gid >> 6;   // one wave per code
    int lane = threadIdx.x & 63;
    float4 v = *(const float4*)(emb + (size_t)code * ZD + lane * 4);
    float s = v.x*v.x + v.y*v.y + v.z*v.z + v.w*v.w;
    #pragma unroll
    for (int off = 32; off; off >>= 1) s += __shfl_down(s, off, 64);
    if (lane == 0) re[code] = s;

    f16x4 hv;
    hv[0] = (_Float16)v.x; hv[1] = (_Float16)v.y;
    hv[2] = (_Float16)v.z; hv[3] = (_Float16)v.w;
    *(f16x4*)(eh + (size_t)code * ZD + lane * 4) = hv;
}

// ---- stage one 32-code half-tile (16KB) via global_load_lds; 8 waves x 2 loads ----
__device__ __forceinline__ void stage_half8(const char* ehc, char* dstbase,
                                            int h, int w, int l) {
    const int srow = h * 16384;             // 32 codes * 512B
    #pragma unroll
    for (int j = 0; j < 2; ++j) {
        const int gi  = w * 2 + j;          // 0..15
        const int c   = 2 * gi + (l >> 5);  // local code this lane's 16B lands in
        const int kbs = (l & 31) * 16;
        const int off = srow + c * 512 + (kbs ^ ((c & 7) << 4));
        __builtin_amdgcn_global_load_lds((gch*)(ehc + off),
                                         (lch*)(dstbase + gi * 1024), 16, 0, 0);
    }
}

// ---- one 32-code compute phase: 16 ds_read_b128 + 16 MFMA (1 rowgroup, split chains) ----
__device__ __forceinline__ void compute_phase16(const char* hb, int h,
                                                const f16x8 (&ah)[8], const float* reL,
                                                float (&v1)[4], float (&v2)[4], int (&i1)[4],
                                                int lane15, int lk) {
    #pragma unroll
    for (int cg = 0; cg < 2; ++cg) {
        const int c  = cg * 16 + lane15;        // local code 0..31
        const int sw = (lane15 & 7) << 4;       // c&7 == lane15&7
        f16x8 bh[8];
        #pragma unroll
        for (int ks = 0; ks < 8; ++ks)
            bh[ks] = *(const f16x8*)(hb + c * 512 + ((lk * 16 + ks * 64) ^ sw));

        f32x4 ae = {0.f, 0.f, 0.f, 0.f};    // 2 independent 4-chains for ILP
        f32x4 ao = {0.f, 0.f, 0.f, 0.f};
        __builtin_amdgcn_s_setprio(1);
        #pragma unroll
        for (int ks = 0; ks < 4; ++ks) {
            ae = __builtin_amdgcn_mfma_f32_16x16x32_f16(ah[2 * ks],     bh[2 * ks],     ae, 0, 0, 0);
            ao = __builtin_amdgcn_mfma_f32_16x16x32_f16(ah[2 * ks + 1], bh[2 * ks + 1], ao, 0, 0, 0);
        }
        __builtin_amdgcn_s_setprio(0);

        const int codeg = h * 32 + c;
        const float rc = reL[codeg];
        #pragma unroll
        for (int r = 0; r < 4; ++r) {
            float s0 = fmaf(-2.f, ae[r] + ao[r], rc);
            float n2 = fminf(fmaxf(v1[r], s0), v2[r]);           // med3(v1,v2,s0)
            i1[r] = (s0 < v1[r]) ? codeg : i1[r];
            v1[r] = fminf(v1[r], s0);
            v2[r] = n2;
        }
    }
}

// ---------------- fused argmin + out-write + loss partial + idx (r22 verbatim) ----------------
__global__ __launch_bounds__(512, 4)
void vq_argmin_mfma(const float* __restrict__ z, const _Float16* __restrict__ eh,
                    const float* __restrict__ emb, const float* __restrict__ re,
                    float* __restrict__ out, float* __restrict__ lossP,
                    int* __restrict__ idx, int* __restrict__ cnt,
                    int* __restrict__ flags) {
    __shared__ __align__(16) char lds[53248];   // ring 3x16KB | reL 4KB
    float* reL    = (float*)(lds + 49152);      // 1024 f32
    int*   idsL   = (int*)lds;                  // epilogue alias (ring dead by then)
    float* wlossL = (float*)(lds + 1024);       // 8 f32, epilogue alias

    const int tid = threadIdx.x;
    const int w   = tid >> 6;       // 0..7
    const int l   = tid & 63;
    const int lane15 = l & 15;
    const int lk     = l >> 4;
    const int r0  = blockIdx.x * 128;
    const int b   = r0 >> 12;
    const int t0  = r0 & 4095;
    const char* ehc = (const char*)eh;

    *(float2*)(reL + tid * 2) = *(const float2*)(re + tid * 2);

    // ---- z prologue: coalesced glds staging, 4 rounds of 64 c, 4KB/wave scratch ----
    f16x8 ah[8];
    float zsq = 0.f;
    {
        const char* zb = (const char*)(z + (size_t)b * ZD * TT + t0 + w * 16);
        char* zdst = lds + w * 4096;
        #pragma unroll
        for (int round = 0; round < 4; ++round) {
            #pragma unroll
            for (int j = 0; j < 4; ++j) {
                const int cl = j * 16 + (l >> 2);
                const int tb = (l & 3) * 16;
                const int c  = round * 64 + cl;
                const char* src = zb + (size_t)c * TT * 4 + tb;
                __builtin_amdgcn_global_load_lds((gch*)src, (lch*)(zdst + j * 1024),
                                                 16, 0, 0);
            }
            asm volatile("s_waitcnt vmcnt(0)" ::: "memory");
            __builtin_amdgcn_sched_barrier(0);
            #pragma unroll
            for (int ks2 = 0; ks2 < 2; ++ks2) {
                const int cl0 = ks2 * 32 + lk * 8;      // local c within round
                f16x8 h;
                #pragma unroll
                for (int j = 0; j < 8; ++j) {
                    float v = *(const float*)(zdst + (cl0 + j) * 64 + lane15 * 4);
                    zsq = fmaf(v, v, zsq);
                    h[j] = (_Float16)v;
                }
                ah[round * 2 + ks2] = h;    // global ks = round*2 + ks2
            }
            asm volatile("s_waitcnt lgkmcnt(0)" ::: "memory");  // reads done before reuse
            __builtin_amdgcn_sched_barrier(0);
        }
    }
    zsq += __shfl_xor(zsq, 16, 64);
    zsq += __shfl_xor(zsq, 32, 64);

    float v1[4], v2[4];
    int   i1[4];
    #pragma unroll
    for (int r = 0; r < 4; ++r) { v1[r] = 3.4e38f; v2[r] = 3.4e38f; i1[r] = 0; }

    // all waves done using ring as z-scratch; drain, then begin e-staging (depth 2)
    asm volatile("s_waitcnt vmcnt(0) lgkmcnt(0)" ::: "memory");
    __syncthreads();
    stage_half8(ehc, lds,         0, w, l);
    stage_half8(ehc, lds + 16384, 1, w, l);

    // Ring-3: phase h reads buf[h%3]; stage(h+2) (after barrier h) writes
    // buf[(h-1)%3], whose reads finished before barrier h. vmcnt(2) = stage h landed.
    for (int h = 0; h < 31; ++h) {
        asm volatile("s_waitcnt vmcnt(2)" ::: "memory");
        __builtin_amdgcn_sched_barrier(0);
        __builtin_amdgcn_s_barrier();
        if (h < 30) stage_half8(ehc, lds + ((h + 2) % 3) * 16384, h + 2, w, l);
        compute_phase16(lds + (h % 3) * 16384, h, ah, reL, v1, v2, i1, lane15, lk);
    }
    asm volatile("s_waitcnt vmcnt(0)" ::: "memory");
    __builtin_amdgcn_sched_barrier(0);
    __builtin_amdgcn_s_barrier();
    compute_phase16(lds + (31 % 3) * 16384, 31, ah, reL, v1, v2, i1, lane15, lk);

    // reduce across the 16 lanes holding different codes (same rows)
    #pragma unroll
    for (int off = 1; off < 16; off <<= 1) {
        #pragma unroll
        for (int r = 0; r < 4; ++r) {
            float ov1 = __shfl_xor(v1[r], off, 64);
            int   oi1 = __shfl_xor(i1[r], off, 64);
            float ov2 = __shfl_xor(v2[r], off, 64);
            float nv2 = fminf(fmaxf(v1[r], ov1), fminf(v2[r], ov2));
            if (ov1 < v1[r] || (ov1 == v1[r] && oi1 < i1[r])) { v1[r] = ov1; i1[r] = oi1; }
            v2[r] = nv2;
        }
    }

    // zsq of row (lk*4 + rr) -- FULL-WAVE shuffles (r13 lesson)
    float zsr[4];
    #pragma unroll
    for (int r = 0; r < 4; ++r) zsr[r] = __shfl(zsq, lk * 4 + r, 64);

    __syncthreads();    // ring dead -> alias idsL/wlossL safely
    float lossw = 0.f;
    if (lane15 == 0) {
        #pragma unroll
        for (int r = 0; r < 4; ++r) {
            const int row = w * 16 + lk * 4 + r;      // local row 0..127
            idsL[row] = i1[r];
            const bool fl = (v2[r] - v1[r] < TAU);
            lossw += fl ? zsr[r] : (zsr[r] + v1[r]);
            if (fl) {
                int p = atomicAdd(cnt, 1);
                if (p < FLAGCAP) flags[p] = (r0 + row) | (i1[r] << 16);
            }
        }
    }
    lossw += __shfl_xor(lossw, 16, 64);
    lossw += __shfl_xor(lossw, 32, 64);
    if (l == 0) wlossL[w] = lossw;
    __syncthreads();

    if (tid < 128) idx[r0 + tid] = idsL[tid];
    if (tid == 0) {
        float s = 0.f;
        #pragma unroll
        for (int j = 0; j < 8; ++j) s += wlossL[j];
        lossP[blockIdx.x] = s;
    }

    // out-write: wave w covers c in [32w, 32w+32), all 128 rows
    {
        const int c0 = w * 32;
        float* ob = out + (size_t)b * ZD * TT + t0;
        #pragma unroll
        for (int half = 0; half < 2; ++half) {
            const int tt = half * 64 + l;
            const int ii = idsL[tt];
            const float4* er4 = (const float4*)(emb + (size_t)ii * ZD + c0);
            #pragma unroll
            for (int c4 = 0; c4 < 8; ++c4) {
                float4 ev = er4[c4];
                float* o0 = ob + (size_t)(c0 + c4 * 4) * TT + tt;
                o0[0]      = ev.x;
                o0[TT]     = ev.y;
                o0[2 * TT] = ev.z;
                o0[3 * TT] = ev.w;
            }
        }
    }
}

// ------- fixup (blocks 0..255) + sparsity (blocks 256..383); 1024 threads each -------
// fixup: each thread ONE code, 8 flagged rows/pass.
// sparsity: 8 rows/block, ALL 1024 codes (one code/thread) -> per-row lse directly.
__global__ __launch_bounds__(1024)
void vq_fixspar(const float* __restrict__ z, const float* __restrict__ emb,
                const float* __restrict__ re, const int* __restrict__ cnt,
                const int* __restrict__ flags, float* __restrict__ out,
                int* __restrict__ idx, float* __restrict__ sparLse,
                float* __restrict__ addP) {
    const int tid = threadIdx.x;
    const int w   = tid >> 6;       // 0..15
    const int lane = tid & 63;

    if (blockIdx.x >= 256) {
        // ---- sparsity: 8 rows, one code per thread, complete lse per row ----
        __shared__ __align__(16) float er[8][260];
        __shared__ float wmaxS[8][16];
        __shared__ float wsumS[8][16];
        const int sb = blockIdx.x - 256;        // 0..127
        const int r0 = sb * 8;

        for (int i = tid; i < 8 * 256; i += 1024) er[i >> 8][i & 255] = emb[(size_t)r0 * ZD + i];
        __syncthreads();

        const int c = tid;                      // this thread's code
        const float4* ec = (const float4*)(emb + (size_t)c * ZD);
        float a[8] = {0.f,0.f,0.f,0.f,0.f,0.f,0.f,0.f};
        #pragma unroll 4
        for (int k4 = 0; k4 < ZD / 4; ++k4) {
            float4 e4 = ec[k4];
            #pragma unroll
            for (int r = 0; r < 8; ++r) {
                const float* a4 = &er[r][k4 * 4];
                a[r] = fmaf(e4.x, a4[0], fmaf(e4.y, a4[1],
                       fmaf(e4.z, a4[2], fmaf(e4.w, a4[3], a[r]))));
            }
        }
        #pragma unroll
        for (int r = 0; r < 8; ++r) {
            float m = a[r];
            #pragma unroll
            for (int off = 32; off; off >>= 1) m = fmaxf(m, __shfl_xor(m, off, 64));
            if (lane == 0) wmaxS[r][w] = m;
        }
        __syncthreads();
        float M[8];
        #pragma unroll
        for (int r = 0; r < 8; ++r) {
            float m = wmaxS[r][0];
            #pragma unroll
            for (int j = 1; j < 16; ++j) m = fmaxf(m, wmaxS[r][j]);
            M[r] = m;
            float se = expf(a[r] - m);
            #pragma unroll
            for (int off = 32; off; off >>= 1) se += __shfl_xor(se, off, 64);
            if (lane == 0) wsumS[r][w] = se;
        }
        __syncthreads();
        if (tid < 8) {
            float S = 0.f;
            #pragma unroll
            for (int j = 0; j < 16; ++j) S += wsumS[tid][j];
            sparLse[r0 + tid] = M[tid] + logf(S);
        }
        return;
    }

    // ---- fixup: each thread ONE code, 8 flagged rows per pass ----
    __shared__ __align__(16) float zs[8][ZD];
    __shared__ u64 sb2[16][8];
    __shared__ int nwS[8];
    __shared__ float addS;
    int n = cnt[0];
    if (n > FLAGCAP) n = FLAGCAP;
    float blkLoss = 0.f;    // meaningful at tid==0 only

    const int c = tid;              // this thread's code (1024 codes exactly)
    const float4* ec = (const float4*)(emb + (size_t)c * ZD);
    const float rc = re[c];

    for (int base = blockIdx.x * 8; base < n; base += 256 * 8) {
        const int nr = (n - base < 8) ? (n - base) : 8;
        __syncthreads();
        for (int i = tid; i < nr * 256; i += 1024) {
            const int r = i >> 8, k = i & 255;
            const int rowg = flags[base + r] & 0xFFFF;
            zs[r][k] = z[(size_t)(rowg >> 12) * ZD * TT + (size_t)k * TT + (rowg & 4095)];
        }
        __syncthreads();

        float a[8] = {0.f,0.f,0.f,0.f,0.f,0.f,0.f,0.f};
        #pragma unroll 4
        for (int k4 = 0; k4 < ZD / 4; ++k4) {
            float4 e4 = ec[k4];
            #pragma unroll
            for (int r = 0; r < 8; ++r) {
                const float* a4 = &zs[r][k4 * 4];
                a[r] = fmaf(e4.x, a4[0], fmaf(e4.y, a4[1],
                       fmaf(e4.z, a4[2], fmaf(e4.w, a4[3], a[r]))));
            }
        }
        #pragma unroll
        for (int r = 0; r < 8; ++r) {
            if (r < nr) {
                float s = fmaf(-2.f, a[r], rc);
                u64 bv = ((u64)flip32(s) << 32) | (u32)c;
                #pragma unroll
                for (int off = 32; off; off >>= 1) {
                    u64 o = (u64)__shfl_xor((long long)bv, off, 64);
                    if (o < bv) bv = o;
                }
                if (lane == 0) sb2[w][r] = bv;
            }
        }
        __syncthreads();
        if (tid == 0) addS = 0.f;
        __syncthreads();
        if (tid < nr) {
            u64 m = sb2[0][tid];
            #pragma unroll
            for (int j = 1; j < 16; ++j) if (sb2[j][tid] < m) m = sb2[j][tid];
            const int nc  = (int)(u32)(m & 0xFFFFFFFFull);
            const float s = unflip32((u32)(m >> 32));
            const int rowg = flags[base + tid] & 0xFFFF;
            const int old  = (flags[base + tid] >> 16) & 1023;
            atomicAdd(&addS, s);
            if (nc != old) { idx[rowg] = nc; nwS[tid] = nc; }
            else nwS[tid] = -1;
        }
        __syncthreads();
        if (tid == 0) blkLoss += addS;
        for (int r = 0; r < nr; ++r) {
            const int nw = nwS[r];
            if (nw >= 0 && tid < 256) {
                const int rowg = flags[base + r] & 0xFFFF;
                out[(size_t)(rowg >> 12) * ZD * TT + (size_t)tid * TT + (rowg & 4095)]
                    = emb[(size_t)nw * ZD + tid];
            }
        }
    }
    if (tid == 0) addP[blockIdx.x] = blkLoss;
}

// ------- final: histogram->perplexity; loss sums; sparsity sum (lse - re) -------
__global__ __launch_bounds__(1024)
void vq_final_kernel(const int* __restrict__ idx, const float* __restrict__ re,
                     const float* __restrict__ sparLse, const float* __restrict__ lossP,
                     const float* __restrict__ addP, float* __restrict__ scal) {
    __shared__ int   histL[4][1024];
    __shared__ float red[1024];
    const int tid = threadIdx.x;
    const int g   = tid >> 8;       // 4 sub-histograms (4 waves each)

    histL[0][tid] = 0; histL[1][tid] = 0; histL[2][tid] = 0; histL[3][tid] = 0;
    __syncthreads();
    #pragma unroll 4
    for (int i = 0; i < 64; ++i)
        atomicAdd(&histL[g][idx[i * 1024 + tid]], 1);
    __syncthreads();
    const int hc = histL[0][tid] + histL[1][tid] + histL[2][tid] + histL[3][tid];
    float p = (float)hc * (1.0f / (float)NROWS);
    red[tid] = -p * logf(p + 1e-10f);
    __syncthreads();
    for (int st = 512; st; st >>= 1) {
        if (tid < st) red[tid] += red[tid + st];
        __syncthreads();
    }
    if (tid == 0) scal[2] = expf(red[0]);
    __syncthreads();

    // loss: 512 argmin partials + 256 fixup partials
    red[tid] = (tid < 512 ? lossP[tid] : 0.f) + ((tid < 256) ? addP[tid] : 0.f);
    __syncthreads();
    for (int st = 512; st; st >>= 1) {
        if (tid < st) red[tid] += red[tid + st];
        __syncthreads();
    }
    if (tid == 0) { scal[0] = red[0]; scal[1] = red[0]; }
    __syncthreads();

    // sparsity: sum over rows of (lse - exact diag re)
    red[tid] = sparLse[tid] - re[tid];
    __syncthreads();
    for (int st = 512; st; st >>= 1) {
        if (tid < st) red[tid] += red[tid + st];
        __syncthreads();
    }
    if (tid == 0) scal[3] = red[0] * (1.0f / (float)KC);
}

extern "C" void kernel_launch(void* const* d_in, const int* in_sizes, int n_in,
                              void* d_out, int out_size, void* d_ws, size_t ws_size,
                              hipStream_t stream) {
    const float* z   = (const float*)d_in[0];
    const float* emb = (const float*)d_in[1];
    float* out = (float*)d_out;
    const size_t NOUT = (size_t)BB * ZD * TT;    // 16777216
    float* scal = out + NOUT;                    // [qut, enc, perp, sparsity]

    float* re      = (float*)d_ws;               // 1024 f32
    int*   cnt     = (int*)(re + KC);            // 4 i32
    int*   flags   = cnt + 4;                    // FLAGCAP i32
    float* sparLse = (float*)(flags + FLAGCAP);  // 1024 f32
    float* lossP   = sparLse + KC;               // 512 f32
    float* addP    = lossP + 512;                // 256 f32
    int*   idx     = (int*)(addP + 256);         // 65536 i32
    _Float16* eh   = (_Float16*)(idx + NROWS);   // 1024*256 f16

    vq_prep_kernel<<<256, 256, 0, stream>>>(emb, eh, re, cnt);
    vq_argmin_mfma<<<NROWS / 128, 512, 0, stream>>>(z, eh, emb, re, out, lossP, idx,
                                                    cnt, flags);
    vq_fixspar<<<384, 1024, 0, stream>>>(z, emb, re, cnt, flags, out, idx,
                                         sparLse, addP);
    vq_final_kernel<<<1, 1024, 0, stream>>>(idx, re, sparLse, lossP, addP, scal);
}